// Round 2
// baseline (81.826 us; speedup 1.0000x reference)
//
#include <hip/hip_runtime.h>

// RandomRectangleErasing: out[b,c,h,w] = (y0<=h<y0+hh && x0<=w<x0+ww) ? 0 : img
// B=64, C=3, H=512, W=512, fp32. Memory-bound streaming op.
// Key idea: b and h are wave-uniform (64 | 128 | 65536), so scalarize the
// per-batch rect params (s_load, scalar cache) and make the row test a
// scalar branch. Off-rect rows (~75%) run a branch-free pure float4 copy.

constexpr int Bc = 64, Cc = 3, Hc = 512, Wc = 512;
constexpr int VPR   = Wc / 4;                    // 128 float4 per row
constexpr int TOTAL = Bc * Cc * Hc * VPR;        // 12,582,912 float4

__device__ __forceinline__ float4 load_masked(
    const float4* __restrict__ in, int idx,
    const int* __restrict__ xs, const int* __restrict__ ys,
    const int* __restrict__ wd, const int* __restrict__ ht)
{
    // idx>>16 (image) and idx>>7 (row) are uniform across the 64-lane wave:
    // waves start at multiples of 64, and 64 divides 128 and 65536.
    const int img = __builtin_amdgcn_readfirstlane(idx >> 16);
    const int b   = img / 3;                                  // scalar magic-mul
    const int h   = __builtin_amdgcn_readfirstlane(idx >> 7) & (Hc - 1);
    const int y0  = ys[b];                                    // s_load (scalar)
    const int y1  = y0 + ht[b];

    if (h >= y0 && h < y1) {          // scalar (wave-uniform) branch
        const int x0 = xs[b];
        const int x1 = x0 + wd[b];
        const int w  = (idx & (VPR - 1)) << 2;                // per-lane
        if (w >= x0 && w + 4 <= x1) {
            return make_float4(0.f, 0.f, 0.f, 0.f);           // skip the load
        }
        float4 v = in[idx];
        if (w + 0 >= x0 && w + 0 < x1) v.x = 0.f;
        if (w + 1 >= x0 && w + 1 < x1) v.y = 0.f;
        if (w + 2 >= x0 && w + 2 < x1) v.z = 0.f;
        if (w + 3 >= x0 && w + 3 < x1) v.w = 0.f;
        return v;
    }
    return in[idx];                   // pure-copy fast path
}

__global__ __launch_bounds__(256) void erase_kernel(
    const float4* __restrict__ in, float4* __restrict__ out,
    const int* __restrict__ xs, const int* __restrict__ ys,
    const int* __restrict__ wd, const int* __restrict__ ht)
{
    const int stride = gridDim.x * blockDim.x;
    for (int i = blockIdx.x * blockDim.x + threadIdx.x; i < TOTAL; i += stride) {
        out[i] = load_masked(in, i, xs, ys, wd, ht);
    }
}

extern "C" void kernel_launch(void* const* d_in, const int* in_sizes, int n_in,
                              void* d_out, int out_size, void* d_ws, size_t ws_size,
                              hipStream_t stream) {
    const float4* in  = (const float4*)d_in[0];
    const int*    wd  = (const int*)d_in[1];
    const int*    ht  = (const int*)d_in[2];
    const int*    xs  = (const int*)d_in[3];
    const int*    ys  = (const int*)d_in[4];
    float4*       out = (float4*)d_out;

    erase_kernel<<<2048, 256, 0, stream>>>(in, out, xs, ys, wd, ht);
}

// Round 3
// 78.865 us; speedup vs baseline: 1.0375x; 1.0375x over previous
//
#include <hip/hip_runtime.h>

// RandomRectangleErasing: out[b,c,h,w] = in-rect ? 0 : img.  fp32, B=64,C=3,H=512,W=512.
// R1 (75.6us): 6 VMEM insts per 16B payload (4 param loads/lane) -> VMEM-issue capped ~5.3 TB/s.
// R2 (81.8us): scalar branch per iter broke unrolling/MLP. REGRESSED.
// R3: block = one 32-row slab of one (b,c) image. Params loaded once/thread before loop;
//     per-component x-masks are loop-invariant; body fully predicated (no branches).

constexpr int Hc = 512, Wc = 512;
constexpr int VPR = Wc / 4;                 // 128 float4 per row
constexpr int ROWS_PER_BLK = 32;            // 32 rows * 128 = 4096 float4 per block
constexpr int CHUNKS_PER_IMG = Hc / ROWS_PER_BLK;   // 16
constexpr int THREADS = 256;
constexpr int ITERS = ROWS_PER_BLK * VPR / THREADS; // 16

__global__ __launch_bounds__(THREADS) void erase_kernel(
    const float4* __restrict__ in, float4* __restrict__ out,
    const int* __restrict__ xs, const int* __restrict__ ys,
    const int* __restrict__ wd, const int* __restrict__ ht)
{
    const int img   = blockIdx.x / CHUNKS_PER_IMG;   // [0, 192)
    const int chunk = blockIdx.x % CHUNKS_PER_IMG;   // [0, 16)
    const int b     = img / 3;

    // one-time per-thread param loads (L1-resident, amortized over 16 iters)
    const int x0 = xs[b];
    const int y0 = ys[b];
    const int x1 = x0 + wd[b];
    const int y1 = y0 + ht[b];

    const int t = threadIdx.x;
    const int w = (t & (VPR - 1)) << 2;              // loop-invariant per thread
    const bool mx0 = (w + 0 >= x0) && (w + 0 < x1);  // per-component x-masks,
    const bool mx1 = (w + 1 >= x0) && (w + 1 < x1);  // computed once
    const bool mx2 = (w + 2 >= x0) && (w + 2 < x1);
    const bool mx3 = (w + 3 >= x0) && (w + 3 < x1);

    const int h_base = chunk * ROWS_PER_BLK + (t >> 7);  // row of iteration 0
    const int base   = img * (Hc * VPR) + chunk * (ROWS_PER_BLK * VPR) + t;

    #pragma unroll
    for (int it = 0; it < ITERS; ++it) {
        const int idx = base + it * THREADS;
        const int h   = h_base + it * (THREADS / VPR);   // +2 per iteration
        const bool in_row = (h >= y0) && (h < y1);
        float4 v = in[idx];
        v.x = (in_row && mx0) ? 0.f : v.x;               // cndmask, branch-free
        v.y = (in_row && mx1) ? 0.f : v.y;
        v.z = (in_row && mx2) ? 0.f : v.z;
        v.w = (in_row && mx3) ? 0.f : v.w;
        out[idx] = v;
    }
}

extern "C" void kernel_launch(void* const* d_in, const int* in_sizes, int n_in,
                              void* d_out, int out_size, void* d_ws, size_t ws_size,
                              hipStream_t stream) {
    const float4* in  = (const float4*)d_in[0];
    const int*    wd  = (const int*)d_in[1];
    const int*    ht  = (const int*)d_in[2];
    const int*    xs  = (const int*)d_in[3];
    const int*    ys  = (const int*)d_in[4];
    float4*       out = (float4*)d_out;

    const int blocks = 64 * 3 * CHUNKS_PER_IMG;      // 3072
    erase_kernel<<<blocks, THREADS, 0, stream>>>(in, out, xs, ys, wd, ht);
}